// Round 5
// baseline (68.347 us; speedup 1.0000x reference)
//
#include <hip/hip_runtime.h>
#include <hip/hip_bf16.h>
#include <math.h>

// Problem constants (from setup_inputs / reference)
#define CLASSES     5
#define C_DIM       64
#define HW          441            // 21*21
#define B_ANCH      32
#define NSUP        25             // L*S support images
#define NROWS       (B_ANCH*HW)    // 14112 query rows
#define MSUP        (NSUP*HW)      // 11025 support descriptors
#define PER_CLS     (MSUP/CLASSES) // 2205 per class
#define TILE_COLS   128
#define NTILES      18             // ceil(2205/128) -> pad to 2304
#define PER_CLS_PAD (NTILES*TILE_COLS)      // 2304
#define NPAD        (PER_CLS_PAD - PER_CLS) // 99 zero-filled pad rows/class
#define ROW_BYTES   (C_DIM*2)      // 128 B per bf16 descriptor row
#define COL_SPLIT   4              // column-tile slices (grid.z)
#define ROWS_PER_BLK 256           // 4 waves x 64 rows

#define NEG_INF  (-1e30f)

typedef __bf16 bf16x8 __attribute__((ext_vector_type(8)));
typedef float  f32x4  __attribute__((ext_vector_type(4)));

// top-3 insert via med3: 3 independent ops; t0 >= t1 >= t2 invariant.
#define TOP3_INS(v, t0, t1, t2) do {                              \
    float _v = (v);                                               \
    float _n0 = fmaxf(_v, (t0));                                  \
    float _n1 = __builtin_amdgcn_fmed3f(_v, (t0), (t1));          \
    float _n2 = __builtin_amdgcn_fmed3f(_v, (t1), (t2));          \
    (t0) = _n0; (t1) = _n1; (t2) = _n2; } while (0)

typedef __attribute__((address_space(1))) const void g_void;
typedef __attribute__((address_space(3))) void l_void;
__device__ __forceinline__ void gload_lds16(const void* g, void* l) {
    __builtin_amdgcn_global_load_lds((g_void*)g, (l_void*)l, 16, 0, 0);
}

// ---------------------------------------------------------------------------
// Kernel 1: L2-normalize all rows (support + anchor) into row-major bf16.
// Support -> sb with per-class row stride PER_CLS_PAD; pad rows zero-filled.
// ---------------------------------------------------------------------------
__global__ __launch_bounds__(256) void norm_rows_kernel(
    const float* __restrict__ anchor, const float* __restrict__ support,
    __bf16* __restrict__ qb, __bf16* __restrict__ sb) {
    int r = blockIdx.x * 256 + threadIdx.x;
    const int total_main = MSUP + NROWS;
    if (r >= total_main) {
        int i = r - total_main;                    // pad-row zero fill
        if (i < CLASSES * NPAD) {
            int cls = i / NPAD, ix = PER_CLS + i % NPAD;
            __bf16* op = sb + ((size_t)cls * PER_CLS_PAD + ix) * C_DIM;
            bf16x8 z = {};
            #pragma unroll
            for (int c0 = 0; c0 < C_DIM; c0 += 8) *(bf16x8*)(op + c0) = z;
        }
        return;
    }
    bool isSup = r < MSUP;
    int rc = isSup ? r : r - MSUP;
    const float* in = isSup ? support : anchor;
    int img = rc / HW, p = rc % HW;
    const float* base = in + (size_t)img * C_DIM * HW + p;
    float q[C_DIM];
    float ss = 0.f;
    #pragma unroll
    for (int c = 0; c < C_DIM; ++c) { q[c] = base[c * HW]; ss += q[c] * q[c]; }
    float sc = rsqrtf(ss);
    __bf16* op;
    if (isSup) {
        int cls = rc / PER_CLS, ix = rc - cls * PER_CLS;
        op = sb + ((size_t)cls * PER_CLS_PAD + ix) * C_DIM;
    } else {
        op = qb + (size_t)rc * C_DIM;
    }
    #pragma unroll
    for (int c0 = 0; c0 < C_DIM; c0 += 8) {
        bf16x8 v;
        #pragma unroll
        for (int j = 0; j < 8; ++j) v[j] = (__bf16)(q[c0 + j] * sc);
        *(bf16x8*)(op + c0) = v;
    }
}

// ---------------------------------------------------------------------------
// Kernel 2: MFMA GEMM + partial top-3 per (row, class, split).
// Grid (56, 5, 4), block 256 = 4 waves. Wave owns 64 rows (M_rep=4 A-frags
// in regs); each B-frag pair feeds 8 MFMAs. B staged to LDS fragment-major
// via pre-permuted global source (linear LDS dest) -> conflict-free
// ds_read_b128 at uniform_base + lane*16. Double-buffered, 1 barrier/tile.
// Split z covers tiles {0-4},{5-9},{10-13},{14-17}; raw top-3 written to
// part[row][cls][split][3] (sigmoid deferred, monotone).
// A/B frag: row/col = lane&15, k = (lane>>4)*8+[0..7].
// C/D: col = lane&15, row = (lane>>4)*4 + reg.   (validated rounds 2-4)
// ---------------------------------------------------------------------------
__global__ __launch_bounds__(256) void knn_mfma_kernel(
    const __bf16* __restrict__ qb, const __bf16* __restrict__ sb,
    float* __restrict__ part) {
    __shared__ bf16x8 smem[2][8][2][64];   // [buf][s][h][lane] = 32 KB

    int lane = threadIdx.x & 63;
    int w    = threadIdx.x >> 6;
    int lr   = lane & 15;      // A-row / B-col index
    int kg   = lane >> 4;      // k-group
    int cls  = blockIdx.y;
    int split = blockIdx.z;
    int tbase  = split < 2 ? split * 5 : 10 + (split - 2) * 4;
    int tcount = split < 2 ? 5 : 4;
    int rowbase = blockIdx.x * ROWS_PER_BLK + w * 64;

    // A fragments for 4 row-blocks of 16 (clamped on the ragged tail)
    bf16x8 a0[4], a1[4];
    #pragma unroll
    for (int r = 0; r < 4; ++r) {
        int arow = rowbase + r * 16 + lr;
        int arc  = arow < NROWS ? arow : NROWS - 1;
        const bf16x8* qrow = (const bf16x8*)(qb + (size_t)arc * C_DIM);
        a0[r] = qrow[kg];
        a1[r] = qrow[4 + kg];
    }

    float t0[4][4], t1[4][4], t2[4][4];
    #pragma unroll
    for (int r = 0; r < 4; ++r)
        #pragma unroll
        for (int j = 0; j < 4; ++j) {
            t0[r][j] = NEG_INF; t1[r][j] = NEG_INF; t2[r][j] = NEG_INF;
        }

    const char* sbCls = (const char*)sb + (size_t)cls * PER_CLS_PAD * ROW_BYTES;
    int laneOff = lr * ROW_BYTES + kg * 16;   // per-lane source permutation

    auto stage = [&](int buf, int t) {
        const char* tb = sbCls + (size_t)t * (TILE_COLS * ROW_BYTES);
        #pragma unroll
        for (int i = 0; i < 4; ++i) {
            int pr = w + 4 * i;
            int s = pr >> 1, h = pr & 1;
            gload_lds16(tb + s * (16 * ROW_BYTES) + h * 64 + laneOff,
                        &smem[buf][s][h][0]);
        }
    };

    stage(0, tbase);
    #pragma unroll 1
    for (int tt = 0; tt < tcount; ++tt) {
        __syncthreads();               // staged tile ready (vmcnt drained)
        int buf = tt & 1;
        if (tt + 1 < tcount) stage(buf ^ 1, tbase + tt + 1);
        int tile = tbase + tt;
        if (tile < NTILES - 1) {
            #pragma unroll
            for (int s = 0; s < 8; ++s) {
                bf16x8 b0 = smem[buf][s][0][lane];
                bf16x8 b1 = smem[buf][s][1][lane];
                #pragma unroll
                for (int r = 0; r < 4; ++r) {
                    f32x4 acc = {0.f, 0.f, 0.f, 0.f};
                    acc = __builtin_amdgcn_mfma_f32_16x16x32_bf16(a0[r], b0, acc, 0, 0, 0);
                    acc = __builtin_amdgcn_mfma_f32_16x16x32_bf16(a1[r], b1, acc, 0, 0, 0);
                    #pragma unroll
                    for (int j = 0; j < 4; ++j)
                        TOP3_INS(acc[j], t0[r][j], t1[r][j], t2[r][j]);
                }
            }
        } else {
            // tile 17: s=0 fully valid (cols 2176-2191); s=1 valid iff lr<13;
            // s>=2 entirely pad -> skipped. SELECT mask keeps pads out.
            #pragma unroll
            for (int s = 0; s < 2; ++s) {
                bf16x8 b0 = smem[buf][s][0][lane];
                bf16x8 b1 = smem[buf][s][1][lane];
                bool valid = (s == 0) || (lr < 13);
                #pragma unroll
                for (int r = 0; r < 4; ++r) {
                    f32x4 acc = {0.f, 0.f, 0.f, 0.f};
                    acc = __builtin_amdgcn_mfma_f32_16x16x32_bf16(a0[r], b0, acc, 0, 0, 0);
                    acc = __builtin_amdgcn_mfma_f32_16x16x32_bf16(a1[r], b1, acc, 0, 0, 0);
                    #pragma unroll
                    for (int j = 0; j < 4; ++j) {
                        float v = valid ? acc[j] : NEG_INF;
                        TOP3_INS(v, t0[r][j], t1[r][j], t2[r][j]);
                    }
                }
            }
        }
    }

    // Merge top-3 across the 16 column-lanes per row; store raw partials.
    #pragma unroll
    for (int r = 0; r < 4; ++r) {
        #pragma unroll
        for (int j = 0; j < 4; ++j) {
            float u0 = t0[r][j], u1 = t1[r][j], u2 = t2[r][j];
            #pragma unroll
            for (int off = 1; off < 16; off <<= 1) {
                float v0 = __shfl_xor(u0, off, 64);
                float v1 = __shfl_xor(u1, off, 64);
                float v2 = __shfl_xor(u2, off, 64);
                TOP3_INS(v0, u0, u1, u2);
                TOP3_INS(v1, u0, u1, u2);
                TOP3_INS(v2, u0, u1, u2);
            }
            int row = rowbase + r * 16 + kg * 4 + j;
            if (lr == 0 && row < NROWS) {
                float* pp = part +
                    ((size_t)(row * CLASSES + cls) * COL_SPLIT + split) * 3;
                pp[0] = u0; pp[1] = u1; pp[2] = u2;
            }
        }
    }
}

// ---------------------------------------------------------------------------
// Kernel 3: merge split partial top-3s, sigmoid, reduce over 441 locations.
// One 64-lane block per (b, l); lane owns whole rows (12 contiguous floats).
// ---------------------------------------------------------------------------
__global__ __launch_bounds__(64) void merge_reduce_kernel(
    const float* __restrict__ part, float* __restrict__ out) {
    int bl = blockIdx.x;
    int b = bl / CLASSES;
    int l = bl % CLASSES;
    int lane = threadIdx.x;
    float acc = 0.f;
    for (int p = lane; p < HW; p += 64) {
        int row = b * HW + p;
        const float* pp = part + (size_t)(row * CLASSES + l) * (COL_SPLIT * 3);
        float u0 = NEG_INF, u1 = NEG_INF, u2 = NEG_INF;
        #pragma unroll
        for (int k = 0; k < COL_SPLIT * 3; ++k) TOP3_INS(pp[k], u0, u1, u2);
        acc += 1.f / (1.f + __expf(-u0))
             + 1.f / (1.f + __expf(-u1))
             + 1.f / (1.f + __expf(-u2));
    }
    #pragma unroll
    for (int off = 32; off; off >>= 1) acc += __shfl_xor(acc, off, 64);
    if (lane == 0) out[bl] = acc;
}

// ---------------------------------------------------------------------------
extern "C" void kernel_launch(void* const* d_in, const int* in_sizes, int n_in,
                              void* d_out, int out_size, void* d_ws, size_t ws_size,
                              hipStream_t stream) {
    const float* anchor  = (const float*)d_in[0];
    const float* support = (const float*)d_in[1];
    // d_in[2]=av_num(1), d_in[3]=sav_num(1) -- fixed by setup, ignored.

    // ws: sb bf16[5*2304*64] | qb bf16[NROWS*64] | part f32[NROWS*5*4*3]
    __bf16* sb = (__bf16*)d_ws;
    __bf16* qb = sb + (size_t)CLASSES * PER_CLS_PAD * C_DIM;
    float* part = (float*)(qb + (size_t)NROWS * C_DIM);

    {
        int total = MSUP + NROWS + CLASSES * NPAD;
        dim3 g((total + 255) / 256);
        norm_rows_kernel<<<g, 256, 0, stream>>>(anchor, support, qb, sb);
    }
    {
        dim3 g((NROWS + ROWS_PER_BLK - 1) / ROWS_PER_BLK, CLASSES, COL_SPLIT);
        knn_mfma_kernel<<<g, 256, 0, stream>>>(qb, sb, part);
    }
    {
        dim3 g(B_ANCH * CLASSES);
        merge_reduce_kernel<<<g, 64, 0, stream>>>(part, (float*)d_out);
    }
}

// Round 6
// 66.254 us; speedup vs baseline: 1.0316x; 1.0316x over previous
//
#include <hip/hip_runtime.h>
#include <hip/hip_bf16.h>
#include <math.h>

// Problem constants (from setup_inputs / reference)
#define CLASSES     5
#define C_DIM       64
#define HW          441            // 21*21
#define B_ANCH      32
#define NSUP        25             // L*S support images
#define NROWS       (B_ANCH*HW)    // 14112 query rows
#define MSUP        (NSUP*HW)      // 11025 support descriptors
#define PER_CLS     (MSUP/CLASSES) // 2205 per class
#define TILE_COLS   64
#define TILES_PER_CLS 36           // padded class = 2304 cols
#define PER_CLS_PAD 2304
#define NPAD        (PER_CLS_PAD - PER_CLS) // 99 zero-filled pad rows/class
#define ROW_BYTES   (C_DIM*2)      // 128 B per bf16 descriptor row
#define HALVES      2              // column splits per class (grid.y = 5*2)
#define TILES_PER_HALF 18
#define ROWS_PER_BLK 128           // 4 waves x 32 rows (M_rep=2)

#define NEG_INF  (-1e30f)

typedef __bf16 bf16x8 __attribute__((ext_vector_type(8)));
typedef float  f32x4  __attribute__((ext_vector_type(4)));

// top-3 insert via med3: 3 independent ops; t0 >= t1 >= t2 invariant.
#define TOP3_INS(v, t0, t1, t2) do {                              \
    float _v = (v);                                               \
    float _n0 = fmaxf(_v, (t0));                                  \
    float _n1 = __builtin_amdgcn_fmed3f(_v, (t0), (t1));          \
    float _n2 = __builtin_amdgcn_fmed3f(_v, (t1), (t2));          \
    (t0) = _n0; (t1) = _n1; (t2) = _n2; } while (0)

typedef __attribute__((address_space(1))) const void g_void;
typedef __attribute__((address_space(3))) void l_void;
__device__ __forceinline__ void gload_lds16(const void* g, void* l) {
    __builtin_amdgcn_global_load_lds((g_void*)g, (l_void*)l, 16, 0, 0);
}

// ---------------------------------------------------------------------------
// Kernel 1: L2-normalize all rows (support + anchor) into row-major bf16.
// Support -> sb with per-class row stride PER_CLS_PAD; pad rows zero-filled.
// ---------------------------------------------------------------------------
__global__ __launch_bounds__(256) void norm_rows_kernel(
    const float* __restrict__ anchor, const float* __restrict__ support,
    __bf16* __restrict__ qb, __bf16* __restrict__ sb) {
    int r = blockIdx.x * 256 + threadIdx.x;
    const int total_main = MSUP + NROWS;
    if (r >= total_main) {
        int i = r - total_main;                    // pad-row zero fill
        if (i < CLASSES * NPAD) {
            int cls = i / NPAD, ix = PER_CLS + i % NPAD;
            __bf16* op = sb + ((size_t)cls * PER_CLS_PAD + ix) * C_DIM;
            bf16x8 z = {};
            #pragma unroll
            for (int c0 = 0; c0 < C_DIM; c0 += 8) *(bf16x8*)(op + c0) = z;
        }
        return;
    }
    bool isSup = r < MSUP;
    int rc = isSup ? r : r - MSUP;
    const float* in = isSup ? support : anchor;
    int img = rc / HW, p = rc % HW;
    const float* base = in + (size_t)img * C_DIM * HW + p;
    float q[C_DIM];
    float ss = 0.f;
    #pragma unroll
    for (int c = 0; c < C_DIM; ++c) { q[c] = base[c * HW]; ss += q[c] * q[c]; }
    float sc = rsqrtf(ss);
    __bf16* op;
    if (isSup) {
        int cls = rc / PER_CLS, ix = rc - cls * PER_CLS;
        op = sb + ((size_t)cls * PER_CLS_PAD + ix) * C_DIM;
    } else {
        op = qb + (size_t)rc * C_DIM;
    }
    #pragma unroll
    for (int c0 = 0; c0 < C_DIM; c0 += 8) {
        bf16x8 v;
        #pragma unroll
        for (int j = 0; j < 8; ++j) v[j] = (__bf16)(q[c0 + j] * sc);
        *(bf16x8*)(op + c0) = v;
    }
}

// ---------------------------------------------------------------------------
// Kernel 2: MFMA GEMM + partial top-3 per (row, class-half).
// Grid (111, 10), block 256 = 4 waves; wave owns 32 rows (M_rep=2).
// B staged to LDS fragment-major (pre-permuted global source, linear LDS
// dest -> conflict-free ds_read_b128). THREE buffers, stage 2 tiles ahead,
// counted s_waitcnt vmcnt(2) + raw s_barrier per tile (loads span barriers;
// vmcnt(0) only on the last tile). ds_reads for s-step s+1 issue before the
// MFMA+TOP3 of step s (register pipeline, named regs, static unroll).
// A/B frag: row/col = lane&15, k = (lane>>4)*8+[0..7].
// C/D: col = lane&15, row = (lane>>4)*4 + reg.   (validated rounds 2-5)
// ---------------------------------------------------------------------------
__global__ __launch_bounds__(256) void knn_mfma_kernel(
    const __bf16* __restrict__ qb, const __bf16* __restrict__ sb,
    float* __restrict__ part) {
    __shared__ bf16x8 smem[3][4][2][64];   // [buf][s][h][lane] = 24 KB

    int lane = threadIdx.x & 63;
    int w    = threadIdx.x >> 6;
    int lr   = lane & 15;      // A-row / B-col index
    int kg   = lane >> 4;      // k-group
    int cls  = blockIdx.y >> 1;
    int half = blockIdx.y & 1;
    int tile0 = half * TILES_PER_HALF;          // class-local first tile
    int NT    = half ? (TILES_PER_HALF - 1) : TILES_PER_HALF; // half1: skip all-pad tile 35
    int rowbase = blockIdx.x * ROWS_PER_BLK + w * 32;

    // A fragments for 2 row-blocks of 16 (clamped on the ragged tail)
    bf16x8 a0[2], a1[2];
    #pragma unroll
    for (int r = 0; r < 2; ++r) {
        int arow = rowbase + r * 16 + lr;
        int arc  = arow < NROWS ? arow : NROWS - 1;
        const bf16x8* qrow = (const bf16x8*)(qb + (size_t)arc * C_DIM);
        a0[r] = qrow[kg];
        a1[r] = qrow[4 + kg];
    }

    float t0[2][4], t1[2][4], t2[2][4];
    #pragma unroll
    for (int r = 0; r < 2; ++r)
        #pragma unroll
        for (int j = 0; j < 4; ++j) {
            t0[r][j] = NEG_INF; t1[r][j] = NEG_INF; t2[r][j] = NEG_INF;
        }

    const char* sbCls = (const char*)sb + (size_t)cls * PER_CLS_PAD * ROW_BYTES;
    int laneOff = lr * ROW_BYTES + kg * 16;   // per-lane source permutation

    // stage class-local tile t into buffer buf: 8 granules of 1 KB, 2/wave
    auto stage = [&](int buf, int t) {
        const char* tb = sbCls + (size_t)t * (TILE_COLS * ROW_BYTES);
        #pragma unroll
        for (int i = 0; i < 2; ++i) {
            int pr = w + 4 * i;
            int s = pr >> 1, h = pr & 1;
            gload_lds16(tb + s * (16 * ROW_BYTES) + h * 64 + laneOff,
                        &smem[buf][s][h][0]);
        }
    };

    stage(0, tile0);
    stage(1, tile0 + 1);
    #pragma unroll 1
    for (int tt = 0; tt < NT; ++tt) {
        // counted drain: tile tt's 2 loads done; tile tt+1's 2 stay in flight
        if (tt < NT - 1) asm volatile("s_waitcnt vmcnt(2)" ::: "memory");
        else             asm volatile("s_waitcnt vmcnt(0)" ::: "memory");
        __builtin_amdgcn_s_barrier();
        if (tt + 2 < NT) stage((tt + 2) % 3, tile0 + tt + 2);
        int buf = tt % 3;
        bool tail = half && (tt == NT - 1);   // class-local tile 34
        __builtin_amdgcn_s_setprio(1);
        if (!tail) {
            bf16x8 c0 = smem[buf][0][0][lane];
            bf16x8 c1 = smem[buf][0][1][lane];
            #pragma unroll
            for (int s = 0; s < 4; ++s) {
                bf16x8 n0, n1;
                if (s < 3) {                   // prefetch next s-step
                    n0 = smem[buf][s + 1][0][lane];
                    n1 = smem[buf][s + 1][1][lane];
                }
                #pragma unroll
                for (int r = 0; r < 2; ++r) {
                    f32x4 acc = {0.f, 0.f, 0.f, 0.f};
                    acc = __builtin_amdgcn_mfma_f32_16x16x32_bf16(a0[r], c0, acc, 0, 0, 0);
                    acc = __builtin_amdgcn_mfma_f32_16x16x32_bf16(a1[r], c1, acc, 0, 0, 0);
                    #pragma unroll
                    for (int j = 0; j < 4; ++j)
                        TOP3_INS(acc[j], t0[r][j], t1[r][j], t2[r][j]);
                }
                if (s < 3) { c0 = n0; c1 = n1; }
            }
        } else {
            // tile 34: s=0 (cols 2176-2191) full; s=1 valid iff lr<13;
            // s>=2 entirely pad -> skipped. SELECT mask keeps pads out.
            #pragma unroll
            for (int s = 0; s < 2; ++s) {
                bf16x8 c0 = smem[buf][s][0][lane];
                bf16x8 c1 = smem[buf][s][1][lane];
                bool valid = (s == 0) || (lr < 13);
                #pragma unroll
                for (int r = 0; r < 2; ++r) {
                    f32x4 acc = {0.f, 0.f, 0.f, 0.f};
                    acc = __builtin_amdgcn_mfma_f32_16x16x32_bf16(a0[r], c0, acc, 0, 0, 0);
                    acc = __builtin_amdgcn_mfma_f32_16x16x32_bf16(a1[r], c1, acc, 0, 0, 0);
                    #pragma unroll
                    for (int j = 0; j < 4; ++j) {
                        float v = valid ? acc[j] : NEG_INF;
                        TOP3_INS(v, t0[r][j], t1[r][j], t2[r][j]);
                    }
                }
            }
        }
        __builtin_amdgcn_s_setprio(0);
    }

    // Merge top-3 across the 16 column-lanes per row; store raw partials
    // (sigmoid deferred to the merge kernel — monotone).
    #pragma unroll
    for (int r = 0; r < 2; ++r) {
        #pragma unroll
        for (int j = 0; j < 4; ++j) {
            float u0 = t0[r][j], u1 = t1[r][j], u2 = t2[r][j];
            #pragma unroll
            for (int off = 1; off < 16; off <<= 1) {
                float v0 = __shfl_xor(u0, off, 64);
                float v1 = __shfl_xor(u1, off, 64);
                float v2 = __shfl_xor(u2, off, 64);
                TOP3_INS(v0, u0, u1, u2);
                TOP3_INS(v1, u0, u1, u2);
                TOP3_INS(v2, u0, u1, u2);
            }
            int row = rowbase + r * 16 + kg * 4 + j;
            if (lr == 0 && row < NROWS) {
                float* pp = part +
                    ((size_t)(row * CLASSES + cls) * HALVES + half) * 3;
                pp[0] = u0; pp[1] = u1; pp[2] = u2;
            }
        }
    }
}

// ---------------------------------------------------------------------------
// Kernel 3: merge half partial top-3s, sigmoid, reduce over 441 locations.
// One 64-lane block per (b, l); lane owns whole rows (6 contiguous floats).
// ---------------------------------------------------------------------------
__global__ __launch_bounds__(64) void merge_reduce_kernel(
    const float* __restrict__ part, float* __restrict__ out) {
    int bl = blockIdx.x;
    int b = bl / CLASSES;
    int l = bl % CLASSES;
    int lane = threadIdx.x;
    float acc = 0.f;
    for (int p = lane; p < HW; p += 64) {
        int row = b * HW + p;
        const float* pp = part + (size_t)(row * CLASSES + l) * (HALVES * 3);
        float u0 = NEG_INF, u1 = NEG_INF, u2 = NEG_INF;
        #pragma unroll
        for (int k = 0; k < HALVES * 3; ++k) TOP3_INS(pp[k], u0, u1, u2);
        acc += 1.f / (1.f + __expf(-u0))
             + 1.f / (1.f + __expf(-u1))
             + 1.f / (1.f + __expf(-u2));
    }
    #pragma unroll
    for (int off = 32; off; off >>= 1) acc += __shfl_xor(acc, off, 64);
    if (lane == 0) out[bl] = acc;
}

// ---------------------------------------------------------------------------
extern "C" void kernel_launch(void* const* d_in, const int* in_sizes, int n_in,
                              void* d_out, int out_size, void* d_ws, size_t ws_size,
                              hipStream_t stream) {
    const float* anchor  = (const float*)d_in[0];
    const float* support = (const float*)d_in[1];
    // d_in[2]=av_num(1), d_in[3]=sav_num(1) -- fixed by setup, ignored.

    // ws: sb bf16[5*2304*64] | qb bf16[NROWS*64] | part f32[NROWS*5*2*3]
    __bf16* sb = (__bf16*)d_ws;
    __bf16* qb = sb + (size_t)CLASSES * PER_CLS_PAD * C_DIM;
    float* part = (float*)(qb + (size_t)NROWS * C_DIM);

    {
        int total = MSUP + NROWS + CLASSES * NPAD;
        dim3 g((total + 255) / 256);
        norm_rows_kernel<<<g, 256, 0, stream>>>(anchor, support, qb, sb);
    }
    {
        dim3 g((NROWS + ROWS_PER_BLK - 1) / ROWS_PER_BLK, CLASSES * HALVES);
        knn_mfma_kernel<<<g, 256, 0, stream>>>(qb, sb, part);
    }
    {
        dim3 g(B_ANCH * CLASSES);
        merge_reduce_kernel<<<g, 64, 0, stream>>>(part, (float*)d_out);
    }
}